// Round 1
// 288.976 us; speedup vs baseline: 1.0381x; 1.0381x over previous
//
#include <hip/hip_runtime.h>

// Problem constants
#define B_SZ   64
#define IC_N   128
#define OC_N   128
#define OUT_D  1024
#define L_N    2048

typedef __attribute__((ext_vector_type(8))) __bf16 bf16x8;
typedef __attribute__((ext_vector_type(4))) float  f32x4;

// RNE fp32->bf16, packed pair (lo in low 16 bits).
__device__ __forceinline__ unsigned pack2bf(float lo, float hi) {
    unsigned ul = __builtin_bit_cast(unsigned, lo);
    unsigned uh = __builtin_bit_cast(unsigned, hi);
    ul += 0x7fffu + ((ul >> 16) & 1u);
    uh += 0x7fffu + ((uh >> 16) & 1u);
    return (ul >> 16) | (uh & 0xffff0000u);
}

// ======================= FUSED single-pass kernel ===========================
// Block dg (256 blocks, 1/CU): d = dg*4 + dl (dl=0..3), l-range dg*8 .. dg*8+7.
// Computes full C[64 b][128 oc] x 4 d. x and w each read exactly ONCE from HBM
// (224 MB total traffic floor incl. 32 MB out).
//
// K-loop: 8 chunks of 16 ic. Per chunk, stage x/w slab f32->bf16 into LDS:
//   Xs[dl 4][b 64][kk 32]  bf16 (kk = 2*ic_local + s)  = 16 KB
//   Ws[dl 4][o 128][kk 32] bf16                        = 32 KB
// Row = 32 shorts = 16 dwords -> staging writes 2-way bank aliased (free),
// MFMA fragment reads are contiguous-1KB ds_read_b128 (conflict-free).
// One 16x16x32 MFMA K-step per chunk per tile.
//
// Waves: wv -> (dl = wv&3, oc-half nh = wv>>2). Per wave M=64, N=64 at one dl:
// acc[mt 4][nt 4] f32x4 (64 VGPR), identical fragment mapping to the verified
// round-1 kernel (A: Xs[dl][16mt+col][quad*8], C row = 16mt+4quad+reg).
//
// XCD swizzle: dg = (bid&7)*32 + (bid>>3) -> 32 consecutive dg per XCD so the
// 32B half-sector reads (8-float l-runs) of dg-neighbors merge in L2, and the
// epilogue's 16B d-run stores merge into full lines.
__global__ __launch_bounds__(512)
void lc1d_fused(const float* __restrict__ x, const float* __restrict__ w,
                float* __restrict__ out) {
    __shared__ __align__(16) unsigned smem[12288];   // 48 KB
    unsigned* Xs = smem;          // [dl][b][icl] dwords (dword = (s0,s1) bf16 pair)
    unsigned* Ws = smem + 4096;   // [dl][o][icl] dwords

    const int bid = blockIdx.x;
    const int dg  = (bid & 7) * 32 + (bid >> 3);     // bijection on [0,256)
    const int t = threadIdx.x, wv = t >> 6, lane = t & 63;
    const int col = lane & 15, quad = lane >> 4;

    // staging coords: thread -> (j = which float4 of the 8-float l-run,
    //                            icl = ic within chunk, rb = row base, +16/r)
    const int j   = t & 1;
    const int icl = (t >> 1) & 15;
    const int rb  = t >> 5;                          // 0..15

    const size_t rowoff  = ((size_t)rb * IC_N + icl) * L_N + (size_t)dg * 8 + 4 * j;
    const float* xp = x + rowoff;
    const float* wp = w + rowoff;
    const size_t RSTRIDE = (size_t)16 * IC_N * L_N;  // +16 rows (b or oc)
    const size_t CSTRIDE = (size_t)16 * L_N;         // +16 ic (next chunk)

    // compute coords
    const int dl = wv & 3, nh = wv >> 2;
    const unsigned* xa = Xs + dl * 1024 + col * 16 + quad * 4;                // +mt*256
    const unsigned* wb = Ws + dl * 2048 + (nh * 64 + col) * 16 + quad * 4;    // +nt*256

    f32x4 acc[4][4];
#pragma unroll
    for (int mt = 0; mt < 4; ++mt)
#pragma unroll
        for (int nt = 0; nt < 4; ++nt)
            acc[mt][nt] = (f32x4){0.f, 0.f, 0.f, 0.f};

    // prologue: loads for chunk 0
    float4 xv[4], wvv[8];
#pragma unroll
    for (int r = 0; r < 4; ++r) xv[r]  = *(const float4*)(xp + (size_t)r * RSTRIDE);
#pragma unroll
    for (int r = 0; r < 8; ++r) wvv[r] = *(const float4*)(wp + (size_t)r * RSTRIDE);

    for (int c = 0; c < 8; ++c) {
        __syncthreads();   // previous chunk's fragment reads done

        // ---- convert + store slab: float4 covers l = 4j..4j+3 -> dl = 2j, 2j+1 ----
#pragma unroll
        for (int r = 0; r < 4; ++r) {
            const int b_ = rb + 16 * r;
            Xs[(2 * j)     * 1024 + b_ * 16 + icl] = pack2bf(xv[r].x, xv[r].y);
            Xs[(2 * j + 1) * 1024 + b_ * 16 + icl] = pack2bf(xv[r].z, xv[r].w);
        }
#pragma unroll
        for (int r = 0; r < 8; ++r) {
            const int o_ = rb + 16 * r;
            Ws[(2 * j)     * 2048 + o_ * 16 + icl] = pack2bf(wvv[r].x, wvv[r].y);
            Ws[(2 * j + 1) * 2048 + o_ * 16 + icl] = pack2bf(wvv[r].z, wvv[r].w);
        }
        __syncthreads();

        // ---- issue next chunk's global loads (hide HBM latency under MFMA) ----
        if (c < 7) {
            const float* xq = xp + (size_t)(c + 1) * CSTRIDE;
            const float* wq = wp + (size_t)(c + 1) * CSTRIDE;
#pragma unroll
            for (int r = 0; r < 4; ++r) xv[r]  = *(const float4*)(xq + (size_t)r * RSTRIDE);
#pragma unroll
            for (int r = 0; r < 8; ++r) wvv[r] = *(const float4*)(wq + (size_t)r * RSTRIDE);
        }

        // ---- fragments + 16 MFMAs (one K=32 step: 16 ic x 2 s) ----
        bf16x8 a[4], bfr[4];
#pragma unroll
        for (int mt = 0; mt < 4; ++mt)
            a[mt] = __builtin_bit_cast(bf16x8, *(const uint4*)(xa + mt * 256));
#pragma unroll
        for (int nt = 0; nt < 4; ++nt)
            bfr[nt] = __builtin_bit_cast(bf16x8, *(const uint4*)(wb + nt * 256));
#pragma unroll
        for (int mt = 0; mt < 4; ++mt)
#pragma unroll
            for (int nt = 0; nt < 4; ++nt)
                acc[mt][nt] = __builtin_amdgcn_mfma_f32_16x16x32_bf16(
                    a[mt], bfr[nt], acc[mt][nt], 0, 0, 0);
    }

    // ---- epilogue: LDS transpose (reuse smem) -> float4 d-run stores ----
    // ep[b_l 16][o 128][dl pad 5] floats = 40 KB <= 48 KB.
    const float scale = 0.088388347648318447f;   // 1/sqrt(128)
    float* ep = (float*)smem;
#pragma unroll
    for (int r = 0; r < 4; ++r) {                // b-chunk of 16 (= mt tile r)
        __syncthreads();                         // prior reads of smem done
#pragma unroll
        for (int nt = 0; nt < 4; ++nt)
#pragma unroll
            for (int reg = 0; reg < 4; ++reg) {
                const int b_l = 4 * quad + reg;
                const int o   = nh * 64 + 16 * nt + col;
                ep[(b_l * 128 + o) * 5 + dl] = acc[r][nt][reg] * scale;
            }
        __syncthreads();
#pragma unroll
        for (int pi = 0; pi < 4; ++pi) {
            const int P = t + 512 * pi;          // (b_l, o) pair, 0..2047
            const int b_l = P >> 7, o = P & 127;
            const float* s = &ep[(size_t)P * 5];
            float4 v;
            v.x = s[0]; v.y = s[1]; v.z = s[2]; v.w = s[3];
            *(float4*)&out[(size_t)((16 * r + b_l) * OC_N + o) * OUT_D + dg * 4] = v;
        }
    }
}

// ================================ launch ====================================
extern "C" void kernel_launch(void* const* d_in, const int* in_sizes, int n_in,
                              void* d_out, int out_size, void* d_ws, size_t ws_size,
                              hipStream_t stream) {
    const float* x = (const float*)d_in[0];
    const float* w = (const float*)d_in[1];
    float* out     = (float*)d_out;
    hipLaunchKernelGGL(lc1d_fused, dim3(256), dim3(512), 0, stream, x, w, out);
}

// Round 3
// 286.053 us; speedup vs baseline: 1.0487x; 1.0102x over previous
//
#include <hip/hip_runtime.h>

// Problem constants
#define B_SZ   64
#define IC_N   128
#define OC_N   128
#define OUT_D  1024
#define L_N    2048

typedef __attribute__((ext_vector_type(8))) __bf16 bf16x8;
typedef __attribute__((ext_vector_type(4))) float  f32x4;

// RNE fp32->bf16, packed pair (lo in low 16 bits).
__device__ __forceinline__ unsigned pack2bf(float lo, float hi) {
    unsigned ul = __builtin_bit_cast(unsigned, lo);
    unsigned uh = __builtin_bit_cast(unsigned, hi);
    ul += 0x7fffu + ((ul >> 16) & 1u);
    uh += 0x7fffu + ((uh >> 16) & 1u);
    return (ul >> 16) | (uh & 0xffff0000u);
}

// ======================= FUSED single-pass kernel ===========================
// (resubmit of round-2: bench container failed, no counter evidence obtained)
//  1. Double-buffered LDS (2 x 48 KB) -> ONE barrier per chunk. Hazard proof:
//     wave W's buf-p ds_reads are drained by the __syncthreads (lgkmcnt(0))
//     it must pass before any wave can start the NEXT write to buf-p
//     (2 chunks later).
//  2. 2-chunk-deep register prefetch (A/B sets): chunk c+2's global loads are
//     issued ~2 full phases before their vmcnt-wait at the pack stage, so
//     >=1 chunk (24 MB GPU-wide) stays in flight -> no memory-system drain.
//  3. XCD-phase chunk stagger: phase = bid&7 (constant per XCD under the dg
//     swizzle) rotates the ic-chunk order per XCD -> decorrelates the 8 XCDs'
//     address streams while preserving within-XCD L2 line merging.
// Layouts/fragments identical to the verified round-1 kernel.
__global__ __launch_bounds__(512, 2)
void lc1d_fused(const float* __restrict__ x, const float* __restrict__ w,
                float* __restrict__ out) {
    __shared__ __align__(16) unsigned smem[2][12288];   // 2 x 48 KB

    const int bid = blockIdx.x;
    const int dg  = (bid & 7) * 32 + (bid >> 3);     // bijection on [0,256)
    const int phase = bid & 7;                       // constant per XCD
    const int t = threadIdx.x, wv = t >> 6, lane = t & 63;
    const int col = lane & 15, quad = lane >> 4;

    // staging coords
    const int j   = t & 1;
    const int icl = (t >> 1) & 15;
    const int rb  = t >> 5;                          // 0..15

    const size_t rowoff  = ((size_t)rb * IC_N + icl) * L_N + (size_t)dg * 8 + 4 * j;
    const float* xp = x + rowoff;
    const float* wp = w + rowoff;
    const size_t RSTRIDE = (size_t)16 * IC_N * L_N;  // +16 rows (b or oc)
    const size_t CSTRIDE = (size_t)16 * L_N;         // +16 ic (next chunk)

    // compute coords
    const int dl = wv & 3;
    const int xoff = dl * 1024 + col * 16 + quad * 4;
    const int woff = 4096 + dl * 2048 + ((wv >> 2) * 64 + col) * 16 + quad * 4;

    f32x4 acc[4][4];
#pragma unroll
    for (int mt = 0; mt < 4; ++mt)
#pragma unroll
        for (int nt = 0; nt < 4; ++nt)
            acc[mt][nt] = (f32x4){0.f, 0.f, 0.f, 0.f};

    float4 xvA[4], wvA[8], xvB[4], wvB[8];

    auto load_ab = [&](float4* XV, float4* WV, int c) {
        const float* xq = xp + (size_t)c * CSTRIDE;
        const float* wq = wp + (size_t)c * CSTRIDE;
#pragma unroll
        for (int r = 0; r < 4; ++r) XV[r] = *(const float4*)(xq + (size_t)r * RSTRIDE);
#pragma unroll
        for (int r = 0; r < 8; ++r) WV[r] = *(const float4*)(wq + (size_t)r * RSTRIDE);
    };

    auto store_slab = [&](int buf, const float4* XV, const float4* WV) {
        unsigned* Xs = smem[buf];
        unsigned* Ws = smem[buf] + 4096;
#pragma unroll
        for (int r = 0; r < 4; ++r) {
            const int b_ = rb + 16 * r;
            Xs[(2 * j)     * 1024 + b_ * 16 + icl] = pack2bf(XV[r].x, XV[r].y);
            Xs[(2 * j + 1) * 1024 + b_ * 16 + icl] = pack2bf(XV[r].z, XV[r].w);
        }
#pragma unroll
        for (int r = 0; r < 8; ++r) {
            const int o_ = rb + 16 * r;
            Ws[(2 * j)     * 2048 + o_ * 16 + icl] = pack2bf(WV[r].x, WV[r].y);
            Ws[(2 * j + 1) * 2048 + o_ * 16 + icl] = pack2bf(WV[r].z, WV[r].w);
        }
    };

    auto compute = [&](int buf) {
        const unsigned* xa = smem[buf] + xoff;
        const unsigned* wb = smem[buf] + woff;
        bf16x8 a[4], bfr[4];
#pragma unroll
        for (int mt = 0; mt < 4; ++mt)
            a[mt] = __builtin_bit_cast(bf16x8, *(const uint4*)(xa + mt * 256));
#pragma unroll
        for (int nt = 0; nt < 4; ++nt)
            bfr[nt] = __builtin_bit_cast(bf16x8, *(const uint4*)(wb + nt * 256));
#pragma unroll
        for (int mt = 0; mt < 4; ++mt)
#pragma unroll
            for (int nt = 0; nt < 4; ++nt)
                acc[mt][nt] = __builtin_amdgcn_mfma_f32_16x16x32_bf16(
                    a[mt], bfr[nt], acc[mt][nt], 0, 0, 0);
    };

    // prologue: 2 chunks in flight
    load_ab(xvA, wvA, phase);
    load_ab(xvB, wvB, (phase + 1) & 7);

#pragma unroll
    for (int cc = 0; cc < 8; cc += 2) {
        // even chunk -> buf0 (consumes A; A regs then refilled for cc+2)
        store_slab(0, xvA, wvA);
        __syncthreads();
        if (cc + 2 < 8) load_ab(xvA, wvA, (phase + cc + 2) & 7);
        compute(0);

        // odd chunk -> buf1
        store_slab(1, xvB, wvB);
        __syncthreads();
        if (cc + 3 < 8) load_ab(xvB, wvB, (phase + cc + 3) & 7);
        compute(1);
    }

    // ---- epilogue: LDS transpose (reuse smem[0], 40 KB) -> float4 d-runs ----
    const float scale = 0.088388347648318447f;   // 1/sqrt(128)
    float* ep = (float*)smem;
    const int nh2 = wv >> 2;
#pragma unroll
    for (int r = 0; r < 4; ++r) {                // b-chunk of 16 (= mt tile r)
        __syncthreads();                         // prior reads of smem done
#pragma unroll
        for (int nt = 0; nt < 4; ++nt)
#pragma unroll
            for (int reg = 0; reg < 4; ++reg) {
                const int b_l = 4 * quad + reg;
                const int o   = nh2 * 64 + 16 * nt + col;
                ep[(b_l * 128 + o) * 5 + dl] = acc[r][nt][reg] * scale;
            }
        __syncthreads();
#pragma unroll
        for (int pi = 0; pi < 4; ++pi) {
            const int P = t + 512 * pi;          // (b_l, o) pair, 0..2047
            const int b_l = P >> 7, o = P & 127;
            const float* s = &ep[(size_t)P * 5];
            float4 v;
            v.x = s[0]; v.y = s[1]; v.z = s[2]; v.w = s[3];
            *(float4*)&out[(size_t)((16 * r + b_l) * OC_N + o) * OUT_D + dg * 4] = v;
        }
    }
}

// ================================ launch ====================================
extern "C" void kernel_launch(void* const* d_in, const int* in_sizes, int n_in,
                              void* d_out, int out_size, void* d_ws, size_t ws_size,
                              hipStream_t stream) {
    const float* x = (const float*)d_in[0];
    const float* w = (const float*)d_in[1];
    float* out     = (float*)d_out;
    hipLaunchKernelGGL(lc1d_fused, dim3(256), dim3(512), 0, stream, x, w, out);
}